// Round 9
// baseline (166.604 us; speedup 1.0000x reference)
//
#include <hip/hip_runtime.h>
#include <hip/hip_bf16.h>

// Problem constants (fixed by reference)
#define BATCH 2
#define NPTS  8192
#define BN    (BATCH * NPTS)   // 16384
#define KNN   16
#define HEADS 4
#define HD    128              // HEADS*32
#define CIN   64
#define COUT  128
#define WCOLS 384              // [WqA1 | WkA1 | Wv] columns

using short8  = __attribute__((ext_vector_type(8))) short;
using float4v = __attribute__((ext_vector_type(4))) float;

static __device__ __forceinline__ unsigned short f2bf(float x) {
    unsigned u = __float_as_uint(x);
    u += 0x7fffu + ((u >> 16) & 1u);          // round-to-nearest-even
    return (unsigned short)(u >> 16);
}
static __device__ __forceinline__ float bf_lo(unsigned u) { return __uint_as_float(u << 16); }
static __device__ __forceinline__ float bf_hi(unsigned u) { return __uint_as_float(u & 0xffff0000u); }
static __device__ __forceinline__ unsigned pack2(float a, float b) {
    return (unsigned)f2bf(a) | ((unsigned)f2bf(b) << 16);
}
static __device__ __forceinline__ short8 pack8(float4 lo, float4 hi) {
    union { uint4 u; short8 s; } c;
    c.u = make_uint4(pack2(lo.x, lo.y), pack2(lo.z, lo.w),
                     pack2(hi.x, hi.y), pack2(hi.z, hi.w));
    return c.s;
}

// DPP row ops (row = 16 lanes). row_ror:n ctrl = 0x120+n.
template <int CTRL>
static __device__ __forceinline__ float dpp_mov(float x) {
    return __int_as_float(
        __builtin_amdgcn_update_dpp(0, __float_as_int(x), CTRL, 0xf, 0xf, false));
}
static __device__ __forceinline__ float ror_sum16(float x) {
    x += dpp_mov<0x128>(x);
    x += dpp_mov<0x124>(x);
    x += dpp_mov<0x122>(x);
    x += dpp_mov<0x121>(x);
    return x;
}
static __device__ __forceinline__ float ror_max16(float x) {
    x = fmaxf(x, dpp_mov<0x128>(x));
    x = fmaxf(x, dpp_mov<0x124>(x));
    x = fmaxf(x, dpp_mov<0x122>(x));
    x = fmaxf(x, dpp_mov<0x121>(x));
    return x;
}

// ---------------------------------------------------------------------------
// Kernel P: fold weights (coalesced; lane = output column). Unchanged (R6).
// ---------------------------------------------------------------------------
__global__ __launch_bounds__(256) void prep_kernel(
        const float* __restrict__ Wk, const float* __restrict__ Wv,
        const float* __restrict__ Wq, const float* __restrict__ A1,
        const float* __restrict__ b1, const float* __restrict__ P2,
        const float* __restrict__ bp2, const float* __restrict__ Wout,
        unsigned short* __restrict__ WcatT, unsigned short* __restrict__ WoutT,
        float* __restrict__ P2A1, float* __restrict__ cvec) {
    int W = blockIdx.x * 4 + (threadIdx.x >> 6);
    int lane = threadIdx.x & 63;
    if (W < 384) {
        int kk = W / 6, nb = W % 6;
        int n = nb * 64 + lane;
        if (nb < 4) {
            const float* src = (nb < 2 ? Wq : Wk) + kk * HD;
            int jj = n & (HD - 1);
            float acc = 0.f;
            #pragma unroll 8
            for (int m = 0; m < HD; ++m) acc += src[m] * A1[m * HD + jj];
            WcatT[n * CIN + kk] = f2bf(acc);
        } else {
            WcatT[n * CIN + kk] = f2bf(Wv[kk * HD + (n - 2 * HD)]);
        }
    } else if (W < 640) {
        int u = (W - 384) * 64 + lane;
        int n = u >> 7, kk = u & 127;
        WoutT[u] = f2bf(Wout[kk * COUT + n]);
    } else if (W < 646) {
        int u = (W - 640) * 64 + lane;
        int r = u >> 7, j = u & 127;
        const float* src = P2 + r * HD;
        float acc = 0.f;
        #pragma unroll 8
        for (int m = 0; m < HD; ++m) acc += src[m] * A1[m * HD + j];
        P2A1[u] = acc;
    } else if (W < 648) {
        int j = (W - 646) * 64 + lane;
        float acc = b1[j];
        #pragma unroll 8
        for (int m = 0; m < HD; ++m) acc += bp2[m] * A1[m * HD + j];
        cvec[j] = acc;
    }
}

// ---------------------------------------------------------------------------
// Kernel A (MFMA): QKVb = bf16(F) @ Wcat (+cvec on n<128).
// 16 rows/block -> 1024 blocks (4 blocks/CU for latency hiding).
// No LDS, no barrier: A-frags packed straight from global F (lane ml reads
// its own 32B row slice), B-frags from L2-resident WcatT[n][k].
// Swapped operands: D[row=n][col=m]; lane stores 4 consecutive n (uint2).
// Validated structurally in R8's mega phase Q.
// ---------------------------------------------------------------------------
__global__ __launch_bounds__(256) void qkv_kernel(const float* __restrict__ F,
                                                  const unsigned short* __restrict__ WcatT,
                                                  const float* __restrict__ cvec,
                                                  unsigned short* __restrict__ QKVb) {
    int p0 = blockIdx.x * 16;
    int t = threadIdx.x;
    int w = t >> 6, lane = t & 63;
    int ml = lane & 15, quad = lane >> 4;
    int n0 = w * 96;

    const float* frow = F + (p0 + ml) * CIN;
    short8 a0 = pack8(*(const float4*)(frow + quad * 8),
                      *(const float4*)(frow + quad * 8 + 4));
    short8 a1 = pack8(*(const float4*)(frow + 32 + quad * 8),
                      *(const float4*)(frow + 32 + quad * 8 + 4));

    #pragma unroll
    for (int j = 0; j < 6; ++j) {
        int n = n0 + j * 16 + ml;
        short8 b0 = *(const short8*)(WcatT + n * CIN + quad * 8);
        short8 b1 = *(const short8*)(WcatT + n * CIN + 32 + quad * 8);
        float4v acc = {0.f, 0.f, 0.f, 0.f};
        acc = __builtin_amdgcn_mfma_f32_16x16x32_bf16(b0, a0, acc, 0, 0, 0);
        acc = __builtin_amdgcn_mfma_f32_16x16x32_bf16(b1, a1, acc, 0, 0, 0);
        int nc = n0 + j * 16 + quad * 4;
        float c0 = 0.f, c1 = 0.f, c2 = 0.f, c3 = 0.f;
        if (nc < HD) {
            float4 cv = *(const float4*)(cvec + nc);
            c0 = cv.x; c1 = cv.y; c2 = cv.z; c3 = cv.w;
        }
        *(uint2*)(QKVb + (p0 + ml) * WCOLS + nc) =
            make_uint2(pack2(acc[0] + c0, acc[1] + c1),
                       pack2(acc[2] + c2, acc[3] + c3));
    }
}

// ---------------------------------------------------------------------------
// Kernel B: per-point attention (DPP; unchanged from R6 — 58.5 us known).
// ---------------------------------------------------------------------------
__global__ __launch_bounds__(256) void attn_kernel(
        const float* __restrict__ xyzs, const int* __restrict__ kg,
        const unsigned short* __restrict__ QKVb,
        const float* __restrict__ P1, const float* __restrict__ bp1,
        const float* __restrict__ P2, const float* __restrict__ bp2,
        const float* __restrict__ P2A1,
        const float* __restrict__ A2, const float* __restrict__ b2,
        unsigned short* __restrict__ FUSEDb) {
    int p = blockIdx.x;
    int b = p >> 13;
    int t = threadIdx.x;
    int g = t >> 4, k = t & 15, c0 = g * 8;
    int w = t >> 6;
    int lane = t & 63;

    __shared__ float4 A2s[HD];
    __shared__ float4 lgp[4][16];
    __shared__ float4 hs16[16];
    __shared__ float  ats[64];
    __shared__ float4 hbf[4];

    if (t < HD) A2s[t] = *(const float4*)(A2 + t * 4);

    int idx = kg[p * KNN + k];
    int q = b * NPTS + idx;

    float r0 = xyzs[p*3+0] - xyzs[q*3+0];
    float r1 = xyzs[p*3+1] - xyzs[q*3+1];
    float r2 = xyzs[p*3+2] - xyzs[q*3+2];
    float h0 = fmaxf(r0*P1[0] + r1*P1[3] + r2*P1[6] + bp1[0], 0.f);
    float h1 = fmaxf(r0*P1[1] + r1*P1[4] + r2*P1[7] + bp1[1], 0.f);
    float h2 = fmaxf(r0*P1[2] + r1*P1[5] + r2*P1[8] + bp1[2], 0.f);
    if (g == 0) hs16[k] = make_float4(h0, h1, h2, 0.f);

    uint4 qu = *(const uint4*)(QKVb + p * WCOLS + c0);
    uint4 ku = *(const uint4*)(QKVb + q * WCOLS + HD + c0);
    uint4 vu = *(const uint4*)(QKVb + q * WCOLS + 2 * HD + c0);

    float qz[8] = { bf_lo(qu.x), bf_hi(qu.x), bf_lo(qu.y), bf_hi(qu.y),
                    bf_lo(qu.z), bf_hi(qu.z), bf_lo(qu.w), bf_hi(qu.w) };
    float kr[8] = { bf_lo(ku.x), bf_hi(ku.x), bf_lo(ku.y), bf_hi(ku.y),
                    bf_lo(ku.z), bf_hi(ku.z), bf_lo(ku.w), bf_hi(ku.w) };

    float wa0[8], wa1[8], wa2[8];
    *(float4*)(wa0)     = *(const float4*)(P2A1 + 0*HD + c0);
    *(float4*)(wa0 + 4) = *(const float4*)(P2A1 + 0*HD + c0 + 4);
    *(float4*)(wa1)     = *(const float4*)(P2A1 + 1*HD + c0);
    *(float4*)(wa1 + 4) = *(const float4*)(P2A1 + 1*HD + c0 + 4);
    *(float4*)(wa2)     = *(const float4*)(P2A1 + 2*HD + c0);
    *(float4*)(wa2 + 4) = *(const float4*)(P2A1 + 2*HD + c0 + 4);

    __syncthreads();

    float pl0 = 0.f, pl1 = 0.f, pl2 = 0.f, pl3 = 0.f;
    #pragma unroll
    for (int j = 0; j < 8; ++j) {
        float z = fmaxf(qz[j] - kr[j] + h0*wa0[j] + h1*wa1[j] + h2*wa2[j], 0.f);
        float4 ar = A2s[c0 + j];
        pl0 += z * ar.x; pl1 += z * ar.y; pl2 += z * ar.z; pl3 += z * ar.w;
    }
    pl0 += __shfl_xor(pl0, 16, 64); pl0 += __shfl_xor(pl0, 32, 64);
    pl1 += __shfl_xor(pl1, 16, 64); pl1 += __shfl_xor(pl1, 32, 64);
    pl2 += __shfl_xor(pl2, 16, 64); pl2 += __shfl_xor(pl2, 32, 64);
    pl3 += __shfl_xor(pl3, 16, 64); pl3 += __shfl_xor(pl3, 32, 64);
    if (lane < 16) lgp[w][lane] = make_float4(pl0, pl1, pl2, pl3);
    __syncthreads();

    if (t < 64) {
        int hh = t >> 4, kk = t & 15;
        const float* lp = (const float*)lgp;
        float lgt = b2[hh] + lp[0*64 + kk*4 + hh] + lp[1*64 + kk*4 + hh]
                           + lp[2*64 + kk*4 + hh] + lp[3*64 + kk*4 + hh];
        float m = ror_max16(lgt);
        float e = __expf(lgt - m);
        float s = ror_sum16(e);
        float a = e / s;
        ats[t] = a;
        float4 hv = hs16[kk];
        float hb0 = ror_sum16(a * hv.x);
        float hb1 = ror_sum16(a * hv.y);
        float hb2 = ror_sum16(a * hv.z);
        if (kk == 0) hbf[hh] = make_float4(hb0, hb1, hb2, 0.f);
    }
    __syncthreads();

    float a = ats[w * 16 + k];
    float vr[8] = { bf_lo(vu.x), bf_hi(vu.x), bf_lo(vu.y), bf_hi(vu.y),
                    bf_lo(vu.z), bf_hi(vu.z), bf_lo(vu.w), bf_hi(vu.w) };
    float wv[8];
    #pragma unroll
    for (int j = 0; j < 8; ++j) wv[j] = ror_sum16(a * vr[j]);

    if (k == 0) {
        float4 hb = hbf[w];
        float q0[8], q1[8], q2[8], bpv[8];
        *(float4*)(q0)     = *(const float4*)(P2 + 0*HD + c0);
        *(float4*)(q0 + 4) = *(const float4*)(P2 + 0*HD + c0 + 4);
        *(float4*)(q1)     = *(const float4*)(P2 + 1*HD + c0);
        *(float4*)(q1 + 4) = *(const float4*)(P2 + 1*HD + c0 + 4);
        *(float4*)(q2)     = *(const float4*)(P2 + 2*HD + c0);
        *(float4*)(q2 + 4) = *(const float4*)(P2 + 2*HD + c0 + 4);
        *(float4*)(bpv)     = *(const float4*)(bp2 + c0);
        *(float4*)(bpv + 4) = *(const float4*)(bp2 + c0 + 4);
        float f[8];
        #pragma unroll
        for (int j = 0; j < 8; ++j)
            f[j] = wv[j] + hb.x*q0[j] + hb.y*q1[j] + hb.z*q2[j] + bpv[j];
        uint4 fu;
        fu.x = pack2(f[0], f[1]); fu.y = pack2(f[2], f[3]);
        fu.z = pack2(f[4], f[5]); fu.w = pack2(f[6], f[7]);
        *(uint4*)(FUSEDb + p * HD + c0) = fu;
    }
}

// ---------------------------------------------------------------------------
// Kernel C (MFMA): out = FUSEDb @ Wout + bout.
// 16 rows/block -> 1024 blocks; no LDS, no barrier; A-frags straight from
// global FUSEDb, B-frags from L2-resident WoutT. float4 stores.
// ---------------------------------------------------------------------------
__global__ __launch_bounds__(256) void out_kernel(const unsigned short* __restrict__ FUSEDb,
                                                  const unsigned short* __restrict__ WoutT,
                                                  const float* __restrict__ bout,
                                                  float* __restrict__ out) {
    int p0 = blockIdx.x * 16;
    int t = threadIdx.x;
    int w = t >> 6, lane = t & 63;
    int ml = lane & 15, quad = lane >> 4;
    int n0 = w * 32;

    short8 afr[4];
    #pragma unroll
    for (int ks = 0; ks < 4; ++ks)
        afr[ks] = *(const short8*)(FUSEDb + (p0 + ml) * HD + ks * 32 + quad * 8);

    #pragma unroll
    for (int jn = 0; jn < 2; ++jn) {
        int n = n0 + jn * 16 + ml;
        float4v acc = {0.f, 0.f, 0.f, 0.f};
        #pragma unroll
        for (int ks = 0; ks < 4; ++ks) {
            short8 bfr = *(const short8*)(WoutT + n * HD + ks * 32 + quad * 8);
            acc = __builtin_amdgcn_mfma_f32_16x16x32_bf16(bfr, afr[ks], acc, 0, 0, 0);
        }
        int nc = n0 + jn * 16 + quad * 4;
        float4 bo = *(const float4*)(bout + nc);
        *(float4*)(out + (p0 + ml) * COUT + nc) =
            make_float4(acc[0] + bo.x, acc[1] + bo.y,
                        acc[2] + bo.z, acc[3] + bo.w);
    }
}

// ---------------------------------------------------------------------------
extern "C" void kernel_launch(void* const* d_in, const int* in_sizes, int n_in,
                              void* d_out, int out_size, void* d_ws, size_t ws_size,
                              hipStream_t stream) {
    const float* xyzs = (const float*)d_in[0];
    const float* feat = (const float*)d_in[1];
    const int*   kg   = (const int*)  d_in[2];
    const float* Wk   = (const float*)d_in[3];
    const float* Wv   = (const float*)d_in[4];
    const float* Wq   = (const float*)d_in[5];
    const float* A1   = (const float*)d_in[6];
    const float* b1   = (const float*)d_in[7];
    const float* A2   = (const float*)d_in[8];
    const float* b2   = (const float*)d_in[9];
    const float* P1   = (const float*)d_in[10];
    const float* bp1  = (const float*)d_in[11];
    const float* P2   = (const float*)d_in[12];
    const float* bp2  = (const float*)d_in[13];
    const float* Wout = (const float*)d_in[14];
    const float* bout = (const float*)d_in[15];
    float* out = (float*)d_out;

    float* ws = (float*)d_ws;
    float* cvec = ws;                                      // 128 fp32
    float* P2A1 = ws + 128;                                // 384 fp32
    unsigned short* QKVb   = (unsigned short*)(ws + 512);  // BN*384 bf16
    unsigned short* WcatT  = QKVb + (size_t)BN * WCOLS;    // 384*64 bf16
    unsigned short* WoutT  = WcatT + WCOLS * CIN;          // 128*128 bf16
    unsigned short* FUSEDb = WoutT + COUT * HD;            // BN*128 bf16

    prep_kernel<<<162, 256, 0, stream>>>(
        Wk, Wv, Wq, A1, b1, P2, bp2, Wout, WcatT, WoutT, P2A1, cvec);

    qkv_kernel<<<BN / 16, 256, 0, stream>>>(feat, WcatT, cvec, QKVb);

    attn_kernel<<<BN, 256, 0, stream>>>(
        xyzs, kg, QKVb, P1, bp1, P2, bp2, P2A1, A2, b2, FUSEDb);

    out_kernel<<<BN / 16, 256, 0, stream>>>(FUSEDb, WoutT, bout, out);
}